// Round 13
// baseline (98.498 us; speedup 1.0000x reference)
//
#include <hip/hip_runtime.h>

// ReceptiveFieldNorm, N=16 C=3 H=W=768, fp32. Two iterations (win 51 then 13
// at 256x256). All vertical boxes are horizontal shfl-scans in transposed
// orientation. 5 dispatches (minimal: 4 orientation flips). This revision:
// k_final processes one y-triple (3d,3d+1,3d+2) per 768-thread block -- the 3
// shared map rows are scanned ONCE in parallel (3 scan groups), AB1 rows read
// once; xpose_store spread across 512 threads.

#define N_B 16
#define CCH 3
#define HF 768
#define HL 256
#define SLICE (HL * HL)
#define TOT_L (N_B * SLICE)
#define EPSV 1e-3f

__device__ __forceinline__ int cnt(int i, int P) {
  int hi = i + P; if (hi > HL - 1) hi = HL - 1;
  int lo = i - P; if (lo < 0) lo = 0;
  return hi - lo + 1;
}

// Dual inclusive prefix scan of a 256-wide row per group g into s[g][*].
// 2 syncthreads. Caller must pass a FRESH buffer pair (s,wt) per call
// (double-buffer) -- there is no entry guard.
template <int G>
__device__ __forceinline__ void scan2g(float a, float b, int g, int j,
    float2 (*s)[HL], float2 (*wt)[4]) {
  int lane = j & 63, w = j >> 6;
#pragma unroll
  for (int d = 1; d < 64; d <<= 1) {
    float ta = __shfl_up(a, (unsigned)d);
    float tb = __shfl_up(b, (unsigned)d);
    if (lane >= d) { a += ta; b += tb; }
  }
  if (lane == 63) wt[g][w] = make_float2(a, b);
  __syncthreads();
  float offa = 0.f, offb = 0.f;
  for (int ww = 0; ww < w; ++ww) { float2 t = wt[g][ww]; offa += t.x; offb += t.y; }
  s[g][j] = make_float2(a + offa, b + offb);
  __syncthreads();
}

// Zero-padded box result at position j from prefix array s[g].
template <int P>
__device__ __forceinline__ float2 boxr(const float2 (*s)[HL], int g, int j) {
  int hi = j + P; if (hi > HL - 1) hi = HL - 1;
  int lo = j - P - 1;
  float2 r = s[g][hi];
  if (lo >= 0) { float2 l = s[g][lo]; r.x -= l.x; r.y -= l.y; }
  return r;
}

// Transposed write: threads tid<512 each write one float4 (2 packed float2):
// dst[row][col0 + 2*half .. +2*half+1], row = tid&255, half = tid>>8.
template <int P>
__device__ __forceinline__ void xpose_store(const float2 (*s)[HL], int tid,
    float2* __restrict__ dst, size_t nb, int col0) {
  if (tid < 512) {
    int row = tid & 255, half = tid >> 8;
    float2 r0 = boxr<P>(s, 2 * half, row);
    float2 r1 = boxr<P>(s, 2 * half + 1, row);
    float4* d = (float4*)(dst + nb + (size_t)row * HL + col0);
    d[half] = make_float4(r0.x, r0.y, r1.x, r1.y);
  }
}

// ---------- k1: subsample + channel stats -> UV [N]; H25 scan -> S [T]
__global__ __launch_bounds__(1024) void k1(const float* __restrict__ x,
    float2* __restrict__ UV, float2* __restrict__ Spk) {
  __shared__ float2 sA[4][HL];
  __shared__ float2 wtA[4][4];
  int b = blockIdx.x;
  int n = b >> 6;           // 64 blocks per image
  int ib = (b & 63) << 2;   // first of 4 subsample rows
  int tid = threadIdx.x;
  int g = tid >> 8, j = tid & 255;
  const float* xp = x + (size_t)n * CCH * HF * HF
                  + (size_t)(3 * (ib + g) + 1) * HF + (3 * j + 1);
  float c0 = xp[0], c1 = xp[HF * HF], c2 = xp[2 * HF * HF];
  float uu = (c0 + c1 + c2) * (1.f / 3.f);
  float vv = (c0 * c0 + c1 * c1 + c2 * c2) * (1.f / 3.f);
  size_t nb = (size_t)n * SLICE;
  UV[nb + (size_t)(ib + g) * HL + j] = make_float2(uu, vv);
  scan2g<4>(uu, vv, g, j, sA, wtA);
  xpose_store<25>(sA, tid, Spk, nb, ib);  // S[col=j][row=ib+g]
}

// ---------- k2: [T] scan25 -> box(u,v) -> f -> scan25 -> P [N]
__global__ __launch_bounds__(1024) void k2(const float2* __restrict__ Spk,
    float2* __restrict__ Ppk) {
  __shared__ float2 sA[4][HL], sB[4][HL];
  __shared__ float2 wtA[4][4], wtB[4][4];
  int n = blockIdx.x >> 6, strip = blockIdx.x & 63;
  int tid = threadIdx.x, g = tid >> 8, j = tid & 255;
  int c = strip * 4 + g;  // image col (T-row)
  size_t nb = (size_t)n * SLICE;
  float2 sv = Spk[nb + (size_t)c * HL + j];
  scan2g<4>(sv.x, sv.y, g, j, sA, wtA);   // V25 prefix
  float2 bu = boxr<25>(sA, g, j);         // full box25 at (row j, col c)
  float invM = 1.f / ((float)cnt(j, 25) * (float)cnt(c, 25));
  float xm = bu.x * invM, x2m = bu.y * invM;
  float var = x2m - xm * xm; if (var < 0.f) var = 0.f;
  float inv = 1.f / sqrtf(var + EPSV);
  scan2g<4>(inv, -xm * inv, g, j, sB, wtB);  // V25 prefix of (a,b)
  xpose_store<25>(sB, tid, Ppk, nb, strip * 4);  // P[row=j][col=c]
}

// ---------- k3: [N] scan25 -> A1,B1; iter2 stats; H6 scan -> Q [T]
__global__ __launch_bounds__(1024) void k3(const float2* __restrict__ Ppk,
    const float2* __restrict__ UV, float2* __restrict__ AB1,
    float2* __restrict__ Qpk) {
  __shared__ float2 sA[4][HL], sB[4][HL];
  __shared__ float2 wtA[4][4], wtB[4][4];
  int n = blockIdx.x >> 6, strip = blockIdx.x & 63;
  int tid = threadIdx.x, g = tid >> 8, j = tid & 255;
  int i = strip * 4 + g;  // image row
  size_t nb = (size_t)n * SLICE;
  size_t idx = nb + (size_t)i * HL + j;
  float2 pv = Ppk[idx];
  scan2g<4>(pv.x, pv.y, g, j, sA, wtA);   // H25 prefix of (a,b)
  float2 bb = boxr<25>(sA, g, j);
  float invM = 1.f / ((float)cnt(i, 25) * (float)cnt(j, 25));
  float Av = bb.x * invM, Bv = bb.y * invM;
  AB1[idx] = make_float2(Av, Bv);
  float2 uv = UV[idx];
  float u2 = Av * uv.x + Bv;
  float v2 = Av * Av * uv.y + 2.f * Av * Bv * uv.x + Bv * Bv;
  scan2g<4>(u2, v2, g, j, sB, wtB);       // H6 prefix of (u2,v2)
  xpose_store<6>(sB, tid, Qpk, nb, strip * 4);  // Q[col=j][row=i]
}

// ---------- k4: [T] scan6 -> box6 -> f6 -> scan6 -> R [N]
__global__ __launch_bounds__(1024) void k4(const float2* __restrict__ Qpk,
    float2* __restrict__ Rpk) {
  __shared__ float2 sA[4][HL], sB[4][HL];
  __shared__ float2 wtA[4][4], wtB[4][4];
  int n = blockIdx.x >> 6, strip = blockIdx.x & 63;
  int tid = threadIdx.x, g = tid >> 8, j = tid & 255;
  int c = strip * 4 + g;  // image col
  size_t nb = (size_t)n * SLICE;
  float2 qv = Qpk[nb + (size_t)c * HL + j];
  scan2g<4>(qv.x, qv.y, g, j, sA, wtA);   // V6 prefix
  float2 bu = boxr<6>(sA, g, j);          // full box6 at (row j, col c)
  float invM = 1.f / ((float)cnt(j, 6) * (float)cnt(c, 6));
  float xm = bu.x * invM, x2m = bu.y * invM;
  float var = x2m - xm * xm; if (var < 0.f) var = 0.f;
  float inv = 1.f / sqrtf(var + EPSV);
  scan2g<4>(inv, -xm * inv, g, j, sB, wtB);  // V6 prefix of (a2,b2)
  xpose_store<6>(sB, tid, Rpk, nb, strip * 4);  // R[row=j][col=c]
}

// ---------- bilinear upsample weights for 256 -> 768 (period-3 pattern)
__device__ __forceinline__ void upw(int q, int& i0, int& i1, float& w1) {
  int d = q / 3;
  int r = q - 3 * d;
  if (r == 1) { i0 = d; i1 = d; w1 = 0.f; }
  else if (r == 2) { i0 = d; i1 = d + 1; if (i1 > HL - 1) i1 = HL - 1; w1 = 1.f / 3.f; }
  else { i1 = d; i0 = d - 1; if (i0 < 0) i0 = 0; w1 = 2.f / 3.f; }
}

// ---------- fused output, one y-triple (3d,3d+1,3d+2) per 768-thread block.
// Group g scans map row clamp(d-1+g); slots {0,1,2} = rows {d-1,d,d+1}.
// y=3d   : (1/3)row[d-1] + (2/3)row[d]   -> slots 0,1
// y=3d+1 : row[d] exactly                -> slot 1
// y=3d+2 : (2/3)row[d] + (1/3)row[d+1]   -> slots 1,2
__global__ __launch_bounds__(768) void k_final(
    const float* __restrict__ x, const float2* __restrict__ AB1,
    const float2* __restrict__ Rpk, float* __restrict__ out) {
  __shared__ float2 s[3][HL];
  __shared__ float2 wt[3][4];
  __shared__ float2 ry01[3][HL], ry23[3][HL];
  int nb_ = blockIdx.x;  // n*256 + d
  int d = nb_ & 255, n = nb_ >> 8;
  int tid = threadIdx.x, g = tid >> 8, j = tid & 255;
  size_t mb = (size_t)n * SLICE;
  int rg = d - 1 + g; rg = rg < 0 ? 0 : (rg > HL - 1 ? HL - 1 : rg);
  float2 rv = Rpk[mb + (size_t)rg * HL + j];
  scan2g<3>(rv.x, rv.y, g, j, s, wt);  // 3 map-row scans in parallel
  // per-group slots/weights for the y = 3d+g output row
  int s0 = (g == 0) ? 0 : 1;
  int s1 = (g == 2) ? 2 : 1;
  float wy1 = (g == 0) ? (2.f / 3.f) : ((g == 2) ? (1.f / 3.f) : 0.f);
  float wy0 = 1.f - wy1;
  int r0 = d - 1 + s0; r0 = r0 < 0 ? 0 : (r0 > HL - 1 ? HL - 1 : r0);
  int r1 = d - 1 + s1; r1 = r1 < 0 ? 0 : (r1 > HL - 1 ? HL - 1 : r1);
  float cj6 = (float)cnt(j, 6);
  float2 b0 = boxr<6>(s, s0, j);
  float2 b1 = boxr<6>(s, s1, j);
  float i0f = 1.f / ((float)cnt(r0, 6) * cj6);
  float i1f = 1.f / ((float)cnt(r1, 6) * cj6);
  ry23[g][j] = make_float2(wy0 * b0.x * i0f + wy1 * b1.x * i1f,
                           wy0 * b0.y * i0f + wy1 * b1.y * i1f);
  float2 a0 = AB1[mb + (size_t)r0 * HL + j];
  float2 a1 = AB1[mb + (size_t)r1 * HL + j];
  ry01[g][j] = make_float2(wy0 * a0.x + wy1 * a1.x, wy0 * a0.y + wy1 * a1.y);
  __syncthreads();
  if (j < 192) {
    int y = 3 * d + g;
    float A1c[4], B1c[4], A2c[4], B2c[4];
#pragma unroll
    for (int e = 0; e < 4; ++e) {
      int q = 4 * j + e;
      int ix0, ix1;
      float wx1;
      upw(q, ix0, ix1, wx1);
      float wx0 = 1.f - wx1;
      float2 m0 = ry01[g][ix0], m1 = ry01[g][ix1];
      float2 m2 = ry23[g][ix0], m3 = ry23[g][ix1];
      A1c[e] = wx0 * m0.x + wx1 * m1.x;
      B1c[e] = wx0 * m0.y + wx1 * m1.y;
      A2c[e] = wx0 * m2.x + wx1 * m3.x;
      B2c[e] = wx0 * m2.y + wx1 * m3.y;
    }
    size_t rowbase = ((size_t)(n * CCH) * HF + y) * HF + 4 * j;
#pragma unroll
    for (int c = 0; c < CCH; ++c) {
      const float4 xin = *(const float4*)(x + rowbase + (size_t)c * HF * HF);
      float4 o;
      o.x = A2c[0] * (A1c[0] * xin.x + B1c[0]) + B2c[0];
      o.y = A2c[1] * (A1c[1] * xin.y + B1c[1]) + B2c[1];
      o.z = A2c[2] * (A1c[2] * xin.z + B1c[2]) + B2c[2];
      o.w = A2c[3] * (A1c[3] * xin.w + B1c[3]) + B2c[3];
      *(float4*)(out + rowbase + (size_t)c * HF * HF) = o;
    }
  }
}

extern "C" void kernel_launch(void* const* d_in, const int* in_sizes, int n_in,
                              void* d_out, int out_size, void* d_ws, size_t ws_size,
                              hipStream_t stream) {
  const float* x = (const float*)d_in[0];
  float* out = (float*)d_out;
  const size_t S = (size_t)TOT_L;  // elements per packed (float2) array
  float2 *UV, *Spk, *Ppk, *AB1, *Rpk, *Qpk;
  if (ws_size >= 10 * S * sizeof(float)) {
    float2* w = (float2*)d_ws;
    UV = w; Spk = UV + S; Ppk = Spk + S; AB1 = Ppk + S; Rpk = AB1 + S;
  } else {
    // Buffers k_final reads stay in ws (16 MB); transients live at the head
    // of d_out (each fully written before read, every call).
    AB1 = (float2*)d_ws; Rpk = AB1 + S;
    UV = (float2*)out; Spk = UV + S; Ppk = Spk + S;
  }
  Qpk = Spk;  // S dead after k2; k3 writes Q there, k4 reads

  k1<<<N_B * 64, 1024, 0, stream>>>(x, UV, Spk);
  k2<<<N_B * 64, 1024, 0, stream>>>(Spk, Ppk);
  k3<<<N_B * 64, 1024, 0, stream>>>(Ppk, UV, AB1, Qpk);
  k4<<<N_B * 64, 1024, 0, stream>>>(Qpk, Rpk);
  k_final<<<N_B * HL, 768, 0, stream>>>(x, AB1, Rpk, out);
}